// Round 1
// baseline (200.933 us; speedup 1.0000x reference)
//
#include <hip/hip_runtime.h>
#include <hip/hip_bf16.h>

// Problem constants
#define M_DIM 2048
#define K_DIM 50000
#define N_DIM 256
#define L_PATH 32
// GEMM tiling
#define BMt 128
#define BNt 256
#define BKt 64
#define TOTAL_KSTEPS 782      // ceil(50000/64)
#define KSPLIT 16
#define STEPS_PER_SPLIT 49    // ceil(782/16)
#define MTILES 16             // 2048/128

typedef __bf16 bf16x8 __attribute__((ext_vector_type(8)));
typedef float f32x4 __attribute__((ext_vector_type(4)));
typedef float fx4 __attribute__((ext_vector_type(4)));
typedef unsigned int u32x4 __attribute__((ext_vector_type(4)));

__device__ __forceinline__ unsigned short f2bf(float f) {
  unsigned int u = __float_as_uint(f);
  u += 0x7FFFu + ((u >> 16) & 1u);   // round-to-nearest-even
  return (unsigned short)(u >> 16);
}
__device__ __forceinline__ unsigned int pack2(float lo, float hi) {
  return (unsigned int)f2bf(lo) | ((unsigned int)f2bf(hi) << 16);
}
__device__ __forceinline__ u32x4 pack8(fx4 lo, fx4 hi) {
  u32x4 q;
  q[0] = pack2(lo[0], lo[1]); q[1] = pack2(lo[2], lo[3]);
  q[2] = pack2(hi[0], hi[1]); q[3] = pack2(hi[2], hi[3]);
  return q;
}
__device__ __forceinline__ fx4 ld4g(const float* p, int k, int kmax) {
  fx4 f;
  f[0] = (k + 0 < kmax) ? p[0] : 0.f;
  f[1] = (k + 1 < kmax) ? p[1] : 0.f;
  f[2] = (k + 2 < kmax) ? p[2] : 0.f;
  f[3] = (k + 3 < kmax) ? p[3] : 0.f;
  return f;
}

struct StageRegs { fx4 a[4]; fx4 w[8]; };

// Issue global loads for one K-step into registers (fp32).
__device__ __forceinline__ void issue_stage(const float* Ap, const float* Wp,
                                            int k0, int akoff, int wkoff, StageRegs& r) {
  if (k0 + BKt <= K_DIM) {
#pragma unroll
    for (int i = 0; i < 4; ++i) r.a[i] = *reinterpret_cast<const fx4*>(Ap + k0 + i * 4);
#pragma unroll
    for (int i = 0; i < 8; ++i) r.w[i] = *reinterpret_cast<const fx4*>(Wp + k0 + i * 4);
  } else {
#pragma unroll
    for (int i = 0; i < 4; ++i) r.a[i] = ld4g(Ap + k0 + i * 4, k0 + akoff + i * 4, K_DIM);
#pragma unroll
    for (int i = 0; i < 8; ++i) r.w[i] = ld4g(Wp + k0 + i * 4, k0 + wkoff + i * 4, K_DIM);
  }
}

// x = A (2048x50000) * W^T (W is 256x50000), split-K. bf16 MFMA, fp32 acc.
__global__ __launch_bounds__(512)
void gemm_bf16_splitk(const float* __restrict__ A, const float* __restrict__ W,
                      float* __restrict__ outp, int use_atomic)
{
  // Swizzled LDS tiles: element (row, col) -> idx row*BKt + (col ^ ((row&7)<<3))
  __shared__ __align__(16) unsigned short sA[BMt * BKt];   // 16 KB
  __shared__ __align__(16) unsigned short sW[BNt * BKt];   // 32 KB

  // XCD-bijective block swizzle (gridDim.x = 256, divisible by 8)
  int bid = blockIdx.x;
  int per = gridDim.x >> 3;
  int L = (bid & 7) * per + (bid >> 3);
  int mtile = L & (MTILES - 1);
  int ksp = L >> 4;                 // MTILES == 16

  int m0 = mtile * BMt;
  int s0 = ksp * STEPS_PER_SPLIT;
  int s1 = s0 + STEPS_PER_SPLIT;
  if (s1 > TOTAL_KSTEPS) s1 = TOTAL_KSTEPS;

  int tid = threadIdx.x;
  int wid = tid >> 6, lane = tid & 63;
  int wm = wid >> 2, wn = wid & 3;          // wave grid 2 x 4, each wave 64x64
  int l15 = lane & 15, l4 = lane >> 4;

  // staging roles
  int arow = tid >> 2, aq = tid & 3;        // A: 128 rows x 4 quarters of 16 cols
  int wrow = tid >> 1, wh = tid & 1;        // W: 256 rows x 2 halves of 32 cols
  const float* Ap = A + (size_t)(m0 + arow) * K_DIM + aq * 16;
  const float* Wp = W + (size_t)wrow * K_DIM + wh * 32;
  int akoff = aq * 16, wkoff = wh * 32;

  f32x4 acc[4][4] = {};

  StageRegs cur, nxt;
  issue_stage(Ap, Wp, s0 * BKt, akoff, wkoff, cur);

  for (int s = s0; s < s1; ++s) {
    __syncthreads();   // previous step's LDS consumers done
    // write staged regs -> LDS (fp32 -> bf16, swizzled)
    {
      int swA = (arow & 7) << 3;
      int baseA = arow * BKt;
      *reinterpret_cast<u32x4*>(&sA[baseA + ((aq * 16) ^ swA)]) = pack8(cur.a[0], cur.a[1]);
      *reinterpret_cast<u32x4*>(&sA[baseA + ((aq * 16 + 8) ^ swA)]) = pack8(cur.a[2], cur.a[3]);
      int swW = (wrow & 7) << 3;
      int baseW = wrow * BKt;
#pragma unroll
      for (int c = 0; c < 4; ++c)
        *reinterpret_cast<u32x4*>(&sW[baseW + ((wh * 32 + c * 8) ^ swW)]) =
            pack8(cur.w[2 * c], cur.w[2 * c + 1]);
    }
    // prefetch next step into regs (overlaps MFMA below)
    bool have_next = (s + 1 < s1);
    if (have_next) issue_stage(Ap, Wp, (s + 1) * BKt, akoff, wkoff, nxt);
    __syncthreads();   // LDS tile ready
    // compute 64 K-slices as 2 x (16x16x32)
#pragma unroll
    for (int kk = 0; kk < 2; ++kk) {
      bf16x8 afr[4], bfr[4];
#pragma unroll
      for (int mf = 0; mf < 4; ++mf) {
        int r = wm * 64 + mf * 16 + l15;
        int c = kk * 32 + l4 * 8;
        afr[mf] = *reinterpret_cast<const bf16x8*>(&sA[r * BKt + (c ^ ((r & 7) << 3))]);
      }
#pragma unroll
      for (int nf = 0; nf < 4; ++nf) {
        int r = wn * 64 + nf * 16 + l15;
        int c = kk * 32 + l4 * 8;
        bfr[nf] = *reinterpret_cast<const bf16x8*>(&sW[r * BKt + (c ^ ((r & 7) << 3))]);
      }
#pragma unroll
      for (int mf = 0; mf < 4; ++mf)
#pragma unroll
        for (int nf = 0; nf < 4; ++nf)
          acc[mf][nf] = __builtin_amdgcn_mfma_f32_16x16x32_bf16(afr[mf], bfr[nf], acc[mf][nf], 0, 0, 0);
    }
    if (have_next) cur = nxt;
  }

  // epilogue: C/D layout col = lane&15, row = (lane>>4)*4 + j
  if (use_atomic) {
#pragma unroll
    for (int mf = 0; mf < 4; ++mf)
#pragma unroll
      for (int nf = 0; nf < 4; ++nf)
#pragma unroll
        for (int j = 0; j < 4; ++j) {
          int row = m0 + wm * 64 + mf * 16 + l4 * 4 + j;
          int col = wn * 64 + nf * 16 + l15;
          atomicAdd(&outp[(size_t)row * N_DIM + col], acc[mf][nf][j]);
        }
  } else {
    float* part = outp + (size_t)ksp * (M_DIM * N_DIM);
#pragma unroll
    for (int mf = 0; mf < 4; ++mf)
#pragma unroll
      for (int nf = 0; nf < 4; ++nf)
#pragma unroll
        for (int j = 0; j < 4; ++j) {
          int row = m0 + wm * 64 + mf * 16 + l4 * 4 + j;
          int col = wn * 64 + nf * 16 + l15;
          part[(size_t)row * N_DIM + col] = acc[mf][nf][j];
        }
  }
}

__global__ __launch_bounds__(256)
void reduce_partials(const float* __restrict__ part, float* __restrict__ x) {
  int i = blockIdx.x * 256 + threadIdx.x;   // 0 .. M*N-1
  float s = 0.f;
#pragma unroll
  for (int k = 0; k < KSPLIT; ++k) s += part[(size_t)k * (M_DIM * N_DIM) + i];
  x[i] = s;
}

// One block (256 thr = 4 waves) per sample: gather path vecs, dot with x, BCE.
__global__ __launch_bounds__(256)
void loss_kernel(const float* __restrict__ x, const float* __restrict__ cls_w,
                 const int* __restrict__ nodes, const int* __restrict__ codes,
                 const int* __restrict__ lens, float* __restrict__ per_sample)
{
  int i = blockIdx.x;
  int tid = threadIdx.x;
  int wid = tid >> 6, lane = tid & 63;
  __shared__ float s_logit[L_PATH];
  fx4 xv = *reinterpret_cast<const fx4*>(&x[(size_t)i * N_DIM + lane * 4]);
#pragma unroll
  for (int j = 0; j < 8; ++j) {
    int pos = wid * 8 + j;
    int node = nodes[i * L_PATH + pos];
    fx4 cv = *reinterpret_cast<const fx4*>(&cls_w[(size_t)node * N_DIM + lane * 4]);
    float d = xv[0] * cv[0] + xv[1] * cv[1] + xv[2] * cv[2] + xv[3] * cv[3];
#pragma unroll
    for (int s = 32; s > 0; s >>= 1) d += __shfl_xor(d, s);
    if (lane == 0) s_logit[pos] = d;
  }
  __syncthreads();
  if (wid == 0) {
    int len = lens[i];
    int lenc = len < 1 ? 1 : len;
    float v = 0.f;
    if (lane < L_PATH && lane < lenc) {
      float z = s_logit[lane];
      float y = (float)codes[i * L_PATH + lane];
      v = fmaxf(z, 0.f) - z * y + log1pf(expf(-fabsf(z)));
    }
#pragma unroll
    for (int s = 32; s > 0; s >>= 1) v += __shfl_xor(v, s);
    if (lane == 0) per_sample[i] = v / (float)lenc;
  }
}

__global__ __launch_bounds__(256)
void final_reduce(const float* __restrict__ ps, float* __restrict__ out) {
  int tid = threadIdx.x;
  float s = 0.f;
#pragma unroll
  for (int i = 0; i < M_DIM / 256; ++i) s += ps[tid + i * 256];
  __shared__ float sm[4];
#pragma unroll
  for (int sh = 32; sh > 0; sh >>= 1) s += __shfl_xor(s, sh);
  if ((tid & 63) == 0) sm[tid >> 6] = s;
  __syncthreads();
  if (tid == 0) out[0] = (sm[0] + sm[1] + sm[2] + sm[3]) * (1.0f / (float)M_DIM);
}

extern "C" void kernel_launch(void* const* d_in, const int* in_sizes, int n_in,
                              void* d_out, int out_size, void* d_ws, size_t ws_size,
                              hipStream_t stream) {
  const float* A     = (const float*)d_in[0];   // inputs_vector [2048, 50000]
  const float* W     = (const float*)d_in[1];   // W [256, 50000]
  const float* cls_w = (const float*)d_in[2];   // [49999, 256]
  const int* nodes   = (const int*)d_in[3];     // [2048, 32]
  const int* codes   = (const int*)d_in[4];     // [2048, 32]
  const int* lens    = (const int*)d_in[5];     // [2048]
  float* out = (float*)d_out;

  char* ws = (char*)d_ws;
  const size_t XBYTES = (size_t)M_DIM * N_DIM * sizeof(float);   // 2 MB
  float* x          = (float*)ws;
  float* per_sample = (float*)(ws + XBYTES);                     // 8 KB
  float* partials   = (float*)(ws + (size_t)(4u << 20));         // KSPLIT * 2 MB

  int use_atomic = (ws_size < (size_t)(4u << 20) + (size_t)KSPLIT * XBYTES) ? 1 : 0;

  if (use_atomic) {
    hipMemsetAsync(x, 0, XBYTES, stream);
    gemm_bf16_splitk<<<dim3(MTILES * KSPLIT), dim3(512), 0, stream>>>(A, W, x, 1);
  } else {
    gemm_bf16_splitk<<<dim3(MTILES * KSPLIT), dim3(512), 0, stream>>>(A, W, partials, 0);
    reduce_partials<<<dim3((M_DIM * N_DIM) / 256), dim3(256), 0, stream>>>(partials, x);
  }
  loss_kernel<<<dim3(M_DIM), dim3(256), 0, stream>>>(x, cls_w, nodes, codes, lens, per_sample);
  final_reduce<<<dim3(1), dim3(256), 0, stream>>>(per_sample, out);
}

// Round 2
// 163.871 us; speedup vs baseline: 1.2262x; 1.2262x over previous
//
#include <hip/hip_runtime.h>
#include <hip/hip_bf16.h>

// Problem constants
#define M_DIM 2048
#define K_DIM 50000
#define N_DIM 256
#define L_PATH 32
// GEMM tiling
#define BMt 128
#define BNt 256
#define BKt 64
#define TOTAL_KSTEPS 782      // ceil(50000/64)
#define KSPLIT 16
#define STEPS_PER_SPLIT 49    // ceil(782/16)
#define MTILES 16             // 2048/128

typedef __bf16 bf16x8 __attribute__((ext_vector_type(8)));
typedef float f32x4 __attribute__((ext_vector_type(4)));
typedef float fx4 __attribute__((ext_vector_type(4)));
typedef unsigned int u32x2 __attribute__((ext_vector_type(2)));

__device__ __forceinline__ unsigned short f2bf(float f) {
  unsigned int u = __float_as_uint(f);
  u += 0x7FFFu + ((u >> 16) & 1u);   // round-to-nearest-even
  return (unsigned short)(u >> 16);
}
__device__ __forceinline__ unsigned int pack2(float lo, float hi) {
  return (unsigned int)f2bf(lo) | ((unsigned int)f2bf(hi) << 16);
}

// x = A (2048x50000) * W^T (W is 256x50000), split-K. bf16 MFMA, fp32 acc.
// Single-barrier double-buffered LDS pipeline:
//   per step: MFMA(buf p) ; pack+write regs -> buf p^1 ; issue loads(s+2) ; barrier
__global__ __launch_bounds__(512)
void gemm_bf16_splitk(const float* __restrict__ A, const float* __restrict__ W,
                      float* __restrict__ outp, int use_atomic)
{
  // Swizzled LDS tiles: element (row, col) stored at row*BKt + (col ^ ((row&7)<<3))
  // (XOR applied on 8-col / 16-byte granules)
  __shared__ __align__(16) unsigned short sA[2][BMt * BKt];   // 2 x 16 KB
  __shared__ __align__(16) unsigned short sW[2][BNt * BKt];   // 2 x 32 KB

  // XCD-bijective block swizzle (gridDim.x = 256, divisible by 8).
  // Each XCD ends up with 2 ksp chunks x 16 mtiles -> W chunk shared in L2.
  int bid = blockIdx.x;
  int per = gridDim.x >> 3;
  int Lw = (bid & 7) * per + (bid >> 3);
  int mtile = Lw & (MTILES - 1);
  int ksp = Lw >> 4;                 // MTILES == 16

  int m0 = mtile * BMt;
  int s0 = ksp * STEPS_PER_SPLIT;
  int s1 = s0 + STEPS_PER_SPLIT;
  if (s1 > TOTAL_KSTEPS) s1 = TOTAL_KSTEPS;

  int tid = threadIdx.x;
  int wid = tid >> 6, lane = tid & 63;
  int wm = wid >> 2, wn = wid & 3;          // wave grid 2 x 4, each wave 64x64
  int l15 = lane & 15, l4 = lane >> 4;

  // Coalesced staging roles: 16 lanes x 16B cover one 64-col row chunk (256 B).
  // Per load instruction the wave reads 4 full contiguous rows (1 KB).
  int rowt = tid >> 4;   // 0..31
  int chk  = tid & 15;   // 16B chunk within row (4 fp32 cols)
  const float* Ab = A + (size_t)(m0 + rowt) * K_DIM + chk * 4;
  const float* Wb = W + (size_t)rowt * K_DIM + chk * 4;

  // Per-i LDS write offsets (element index): cols [chk*4, chk*4+4) at swizzled granule
  int offA[4], offW[8];
#pragma unroll
  for (int i = 0; i < 4; ++i) {
    int r = i * 32 + rowt;
    offA[i] = r * BKt + ((((chk >> 1) ^ (r & 7)) << 3) + (chk & 1) * 4);
  }
#pragma unroll
  for (int i = 0; i < 8; ++i) {
    int r = i * 32 + rowt;
    offW[i] = r * BKt + ((((chk >> 1) ^ (r & 7)) << 3) + (chk & 1) * 4);
  }

  fx4 ra[4], rw[8];

  auto load_step = [&](int s) {
    size_t kb = (size_t)s * BKt;
    const float* ap = Ab + kb;
    const float* wp = Wb + kb;
    int k = s * BKt + chk * 4;
    if (k + 4 <= K_DIM) {
#pragma unroll
      for (int i = 0; i < 4; ++i) ra[i] = *reinterpret_cast<const fx4*>(ap + (size_t)i * 32 * K_DIM);
#pragma unroll
      for (int i = 0; i < 8; ++i) rw[i] = *reinterpret_cast<const fx4*>(wp + (size_t)i * 32 * K_DIM);
    } else {
#pragma unroll
      for (int i = 0; i < 4; ++i) {
        fx4 f;
#pragma unroll
        for (int e = 0; e < 4; ++e) f[e] = (k + e < K_DIM) ? ap[(size_t)i * 32 * K_DIM + e] : 0.f;
        ra[i] = f;
      }
#pragma unroll
      for (int i = 0; i < 8; ++i) {
        fx4 f;
#pragma unroll
        for (int e = 0; e < 4; ++e) f[e] = (k + e < K_DIM) ? wp[(size_t)i * 32 * K_DIM + e] : 0.f;
        rw[i] = f;
      }
    }
  };

  auto write_step = [&](int p) {
#pragma unroll
    for (int i = 0; i < 4; ++i) {
      u32x2 v; v[0] = pack2(ra[i][0], ra[i][1]); v[1] = pack2(ra[i][2], ra[i][3]);
      *reinterpret_cast<u32x2*>(&sA[p][offA[i]]) = v;
    }
#pragma unroll
    for (int i = 0; i < 8; ++i) {
      u32x2 v; v[0] = pack2(rw[i][0], rw[i][1]); v[1] = pack2(rw[i][2], rw[i][3]);
      *reinterpret_cast<u32x2*>(&sW[p][offW[i]]) = v;
    }
  };

  f32x4 acc[4][4] = {};

  auto compute = [&](int p) {
#pragma unroll
    for (int kk = 0; kk < 2; ++kk) {
      bf16x8 afr[4], bfr[4];
      int c = kk * 32 + l4 * 8;
#pragma unroll
      for (int mf = 0; mf < 4; ++mf) {
        int r = wm * 64 + mf * 16 + l15;
        afr[mf] = *reinterpret_cast<const bf16x8*>(&sA[p][r * BKt + (c ^ ((r & 7) << 3))]);
      }
#pragma unroll
      for (int nf = 0; nf < 4; ++nf) {
        int r = wn * 64 + nf * 16 + l15;
        bfr[nf] = *reinterpret_cast<const bf16x8*>(&sW[p][r * BKt + (c ^ ((r & 7) << 3))]);
      }
#pragma unroll
      for (int mf = 0; mf < 4; ++mf)
#pragma unroll
        for (int nf = 0; nf < 4; ++nf)
          acc[mf][nf] = __builtin_amdgcn_mfma_f32_16x16x32_bf16(afr[mf], bfr[nf], acc[mf][nf], 0, 0, 0);
    }
  };

  // Prologue: tile s0 into LDS[0]; loads for s0+1 in flight.
  load_step(s0);
  write_step(0);
  if (s0 + 1 < s1) load_step(s0 + 1);
  __syncthreads();

  int p = 0;
  for (int s = s0; s < s1; ++s) {
    compute(p);                    // MFMAs overlap the in-flight loads' drain
    if (s + 1 < s1) {
      write_step(p ^ 1);           // waits vmcnt for tile s+1, packs fp32->bf16
      if (s + 2 < s1) load_step(s + 2);
      __syncthreads();
    }
    p ^= 1;
  }

  // epilogue: C/D layout col = lane&15, row = (lane>>4)*4 + j
  if (use_atomic) {
#pragma unroll
    for (int mf = 0; mf < 4; ++mf)
#pragma unroll
      for (int nf = 0; nf < 4; ++nf)
#pragma unroll
        for (int j = 0; j < 4; ++j) {
          int row = m0 + wm * 64 + mf * 16 + l4 * 4 + j;
          int col = wn * 64 + nf * 16 + l15;
          atomicAdd(&outp[(size_t)row * N_DIM + col], acc[mf][nf][j]);
        }
  } else {
    float* part = outp + (size_t)ksp * (M_DIM * N_DIM);
#pragma unroll
    for (int mf = 0; mf < 4; ++mf)
#pragma unroll
      for (int nf = 0; nf < 4; ++nf)
#pragma unroll
        for (int j = 0; j < 4; ++j) {
          int row = m0 + wm * 64 + mf * 16 + l4 * 4 + j;
          int col = wn * 64 + nf * 16 + l15;
          part[(size_t)row * N_DIM + col] = acc[mf][nf][j];
        }
  }
}

// One block (256 thr = 4 waves) per sample: reduce split-K partials for this row
// into LDS, gather path vecs, dot with x, BCE.
__global__ __launch_bounds__(256)
void loss_kernel(const float* __restrict__ part, int nparts,
                 const float* __restrict__ cls_w,
                 const int* __restrict__ nodes, const int* __restrict__ codes,
                 const int* __restrict__ lens, float* __restrict__ per_sample)
{
  int i = blockIdx.x;
  int tid = threadIdx.x;
  __shared__ float s_x[N_DIM];
  {
    float s = 0.f;
    for (int k = 0; k < nparts; ++k)
      s += part[(size_t)k * (M_DIM * N_DIM) + (size_t)i * N_DIM + tid];
    s_x[tid] = s;
  }
  __syncthreads();

  int wid = tid >> 6, lane = tid & 63;
  __shared__ float s_logit[L_PATH];
  fx4 xv = *reinterpret_cast<const fx4*>(&s_x[lane * 4]);
#pragma unroll
  for (int j = 0; j < 8; ++j) {
    int pos = wid * 8 + j;
    int node = nodes[i * L_PATH + pos];
    fx4 cv = *reinterpret_cast<const fx4*>(&cls_w[(size_t)node * N_DIM + lane * 4]);
    float d = xv[0] * cv[0] + xv[1] * cv[1] + xv[2] * cv[2] + xv[3] * cv[3];
#pragma unroll
    for (int s = 32; s > 0; s >>= 1) d += __shfl_xor(d, s);
    if (lane == 0) s_logit[pos] = d;
  }
  __syncthreads();
  if (wid == 0) {
    int len = lens[i];
    int lenc = len < 1 ? 1 : len;
    float v = 0.f;
    if (lane < L_PATH && lane < lenc) {
      float z = s_logit[lane];
      float y = (float)codes[i * L_PATH + lane];
      v = fmaxf(z, 0.f) - z * y + log1pf(expf(-fabsf(z)));
    }
#pragma unroll
    for (int s = 32; s > 0; s >>= 1) v += __shfl_xor(v, s);
    if (lane == 0) per_sample[i] = v / (float)lenc;
  }
}

__global__ __launch_bounds__(256)
void final_reduce(const float* __restrict__ ps, float* __restrict__ out) {
  int tid = threadIdx.x;
  float s = 0.f;
#pragma unroll
  for (int i = 0; i < M_DIM / 256; ++i) s += ps[tid + i * 256];
  __shared__ float sm[4];
#pragma unroll
  for (int sh = 32; sh > 0; sh >>= 1) s += __shfl_xor(s, sh);
  if ((tid & 63) == 0) sm[tid >> 6] = s;
  __syncthreads();
  if (tid == 0) out[0] = (sm[0] + sm[1] + sm[2] + sm[3]) * (1.0f / (float)M_DIM);
}

extern "C" void kernel_launch(void* const* d_in, const int* in_sizes, int n_in,
                              void* d_out, int out_size, void* d_ws, size_t ws_size,
                              hipStream_t stream) {
  const float* A     = (const float*)d_in[0];   // inputs_vector [2048, 50000]
  const float* W     = (const float*)d_in[1];   // W [256, 50000]
  const float* cls_w = (const float*)d_in[2];   // [49999, 256]
  const int* nodes   = (const int*)d_in[3];     // [2048, 32]
  const int* codes   = (const int*)d_in[4];     // [2048, 32]
  const int* lens    = (const int*)d_in[5];     // [2048]
  float* out = (float*)d_out;

  char* ws = (char*)d_ws;
  const size_t XBYTES = (size_t)M_DIM * N_DIM * sizeof(float);   // 2 MB
  float* per_sample = (float*)ws;                                // 8 KB
  float* x          = (float*)(ws + (size_t)(64u << 10));        // 2 MB (atomic path)
  float* partials   = (float*)(ws + (size_t)(4u << 20));         // KSPLIT * 2 MB

  int use_atomic = (ws_size < (size_t)(4u << 20) + (size_t)KSPLIT * XBYTES) ? 1 : 0;

  if (use_atomic) {
    hipMemsetAsync(x, 0, XBYTES, stream);
    gemm_bf16_splitk<<<dim3(MTILES * KSPLIT), dim3(512), 0, stream>>>(A, W, x, 1);
    loss_kernel<<<dim3(M_DIM), dim3(256), 0, stream>>>(x, 1, cls_w, nodes, codes, lens, per_sample);
  } else {
    gemm_bf16_splitk<<<dim3(MTILES * KSPLIT), dim3(512), 0, stream>>>(A, W, partials, 0);
    loss_kernel<<<dim3(M_DIM), dim3(256), 0, stream>>>(partials, KSPLIT, cls_w, nodes, codes, lens, per_sample);
  }
  final_reduce<<<dim3(1), dim3(256), 0, stream>>>(per_sample, out);
}